// Round 1
// baseline (988.549 us; speedup 1.0000x reference)
//
#include <hip/hip_runtime.h>
#include <hip/hip_bf16.h>

// ---------------------------------------------------------------------------
// AttentionPairBias: B=1, N=1024, H=16, HD=32, D=512, DZ=128
// Stages:
//   1) prep_w:   wWz[j][h] = z_norm_w[j]*Wz[j][h]; csum[h]; cb[h]
//   2) lns:      s_norm = LN(s)                                  [1024,512] f32
//   3) gemm_qkvg: s_norm @ {Wq,Wk,Wv,Wg} -> qT,kT,vT ([H][N][HD], q has
//                 +bq and *HD^-0.5 folded) and g_sig=[N,D] sigmoid
//   4) zbias:    per z-row fused LN+GEMM -> zb[h][q][k] bf16     (HBM-bound)
//   5) attn:     flash attention per (head, q in lanes, k-chunk) -> partials
//   6) combine:  merge 8 k-chunk partials, * g_sig -> og [N,D] f32
//   7) gemm_out: og @ Wo -> d_out [N,D] f32
// ---------------------------------------------------------------------------

#define EPSV 1e-5f

// ---------------- ws layout (bytes) ----------------
#define OFF_SNORM   (0u)
#define OFF_QT      (2097152u)
#define OFF_KT      (4194304u)
#define OFF_VT      (6291456u)
#define OFF_GS      (8388608u)
#define OFF_ZB      (10485760u)     // bf16, 16M elems = 32MB
#define OFF_WWZ     (44040192u)     // 2048 f32
#define OFF_CC      (44048384u)     // 32 f32 (csum[16], cb[16])
#define OFF_PM      (44048512u)     // 8*16*1024 f32
#define OFF_PL      (44572800u)
#define OFF_PO      (45097088u)     // 8*16*1024*32 f32 = 16MB
#define OFF_OG      (61874304u)     // 1024*512 f32

// ---------------------------------------------------------------------------
__global__ __launch_bounds__(256) void prep_w_kernel(
    const float* __restrict__ znw, const float* __restrict__ znb,
    const float* __restrict__ Wz, float* __restrict__ wWz,
    float* __restrict__ cc)
{
    const int t = threadIdx.x;
#pragma unroll
    for (int u = 0; u < 8; ++u) {
        int idx = t + u * 256;              // idx = j*16 + h
        wWz[idx] = znw[idx >> 4] * Wz[idx];
    }
    if (t < 16) {
        float cs = 0.f, cb = 0.f;
        for (int j = 0; j < 128; ++j) {
            float wz = Wz[j * 16 + t];
            cs += znw[j] * wz;
            cb += znb[j] * wz;
        }
        cc[t] = cs;
        cc[16 + t] = cb;
    }
}

// ---------------------------------------------------------------------------
__global__ __launch_bounds__(256) void lns_kernel(
    const float* __restrict__ s, const float* __restrict__ w,
    const float* __restrict__ b, float* __restrict__ sn)
{
    const int lane = threadIdx.x & 63;
    const int wv   = threadIdx.x >> 6;
    const int row  = blockIdx.x * 4 + wv;
    const float* x = s + (size_t)row * 512 + lane * 8;
    float4 a = *(const float4*)x;
    float4 c = *(const float4*)(x + 4);
    float v[8] = {a.x, a.y, a.z, a.w, c.x, c.y, c.z, c.w};
    float ss = 0.f, s2 = 0.f;
#pragma unroll
    for (int u = 0; u < 8; ++u) { ss += v[u]; s2 = fmaf(v[u], v[u], s2); }
#pragma unroll
    for (int m = 1; m < 64; m <<= 1) {
        ss += __shfl_xor(ss, m);
        s2 += __shfl_xor(s2, m);
    }
    float mu  = ss * (1.f / 512.f);
    float var = s2 * (1.f / 512.f) - mu * mu;
    float rs  = rsqrtf(var + EPSV);
    float o[8];
#pragma unroll
    for (int u = 0; u < 8; ++u)
        o[u] = (v[u] - mu) * rs * w[lane * 8 + u] + b[lane * 8 + u];
    float* dst = sn + (size_t)row * 512 + lane * 8;
    *(float4*)dst       = make_float4(o[0], o[1], o[2], o[3]);
    *(float4*)(dst + 4) = make_float4(o[4], o[5], o[6], o[7]);
}

// ---------------------------------------------------------------------------
// QKVG GEMM: A [1024,512] @ W [512,512]; blockIdx.z selects weight/epilogue.
__global__ __launch_bounds__(256) void gemm_qkvg_kernel(
    const float* __restrict__ A,
    const float* __restrict__ Wq, const float* __restrict__ Wk,
    const float* __restrict__ Wv, const float* __restrict__ Wg,
    const float* __restrict__ bq,
    float* __restrict__ qT, float* __restrict__ kT,
    float* __restrict__ vT, float* __restrict__ gS)
{
    __shared__ float As[16][132];
    __shared__ float Bs[16][128];
    const int which = blockIdx.z;
    const float* B = (which == 0) ? Wq : (which == 1) ? Wk : (which == 2) ? Wv : Wg;
    const int n0 = blockIdx.x * 128, m0 = blockIdx.y * 128;
    const int tid = threadIdx.x;
    const int tn = tid & 15, tm = tid >> 4;
    float acc[8][8] = {};

    for (int k0 = 0; k0 < 512; k0 += 16) {
#pragma unroll
        for (int u = 0; u < 2; ++u) {
            int f = tid * 2 + u;
            int i = f >> 2, kk4 = f & 3;
            float4 a4 = *(const float4*)(A + (size_t)(m0 + i) * 512 + k0 + kk4 * 4);
            As[kk4 * 4 + 0][i] = a4.x;
            As[kk4 * 4 + 1][i] = a4.y;
            As[kk4 * 4 + 2][i] = a4.z;
            As[kk4 * 4 + 3][i] = a4.w;
            int kk = f >> 5, j4 = f & 31;
            *(float4*)&Bs[kk][j4 * 4] =
                *(const float4*)(B + (size_t)(k0 + kk) * 512 + n0 + j4 * 4);
        }
        __syncthreads();
#pragma unroll
        for (int kk = 0; kk < 16; ++kk) {
            float a[8], b[8];
            *(float4*)a       = *(const float4*)&As[kk][tm * 8];
            *(float4*)(a + 4) = *(const float4*)&As[kk][tm * 8 + 4];
            *(float4*)b       = *(const float4*)&Bs[kk][tn * 8];
            *(float4*)(b + 4) = *(const float4*)&Bs[kk][tn * 8 + 4];
#pragma unroll
            for (int i = 0; i < 8; ++i)
#pragma unroll
                for (int j = 0; j < 8; ++j)
                    acc[i][j] = fmaf(a[i], b[j], acc[i][j]);
        }
        __syncthreads();
    }

    const int m_base = m0 + tm * 8;
    const int n_base = n0 + tn * 8;
    if (which == 3) {
#pragma unroll
        for (int i = 0; i < 8; ++i) {
            float o[8];
#pragma unroll
            for (int j = 0; j < 8; ++j)
                o[j] = 1.f / (1.f + __expf(-acc[i][j]));
            float* d0 = gS + (size_t)(m_base + i) * 512 + n_base;
            *(float4*)d0       = make_float4(o[0], o[1], o[2], o[3]);
            *(float4*)(d0 + 4) = make_float4(o[4], o[5], o[6], o[7]);
        }
    } else {
        float* dst = (which == 0) ? qT : (which == 1) ? kT : vT;
        const int hh = n_base >> 5, d0 = n_base & 31;
        float bb[8];
#pragma unroll
        for (int j = 0; j < 8; ++j) bb[j] = (which == 0) ? bq[n_base + j] : 0.f;
        const float scl = (which == 0) ? 0.17677669529663687f : 1.f;
#pragma unroll
        for (int i = 0; i < 8; ++i) {
            float o[8];
#pragma unroll
            for (int j = 0; j < 8; ++j)
                o[j] = (acc[i][j] + bb[j]) * scl;
            float* p = dst + (((size_t)hh << 10) + (m_base + i)) * 32 + d0;
            *(float4*)p       = make_float4(o[0], o[1], o[2], o[3]);
            *(float4*)(p + 4) = make_float4(o[4], o[5], o[6], o[7]);
        }
    }
}

// ---------------------------------------------------------------------------
// zbias: one thread per z-row. LN folded into the 128x16 dot:
//   out[h] = rs*(dot[h] - mu*csum[h]) + cb[h]
__global__ __launch_bounds__(256) void zbias_kernel(
    const float* __restrict__ z, const float* __restrict__ wWz,
    const float* __restrict__ cc, __hip_bfloat16* __restrict__ zb)
{
    const int row = blockIdx.x * 256 + threadIdx.x;   // row = q*1024 + k
    const float4* x4 = (const float4*)(z + (size_t)row * 128);
    float acc[16];
#pragma unroll
    for (int h = 0; h < 16; ++h) acc[h] = 0.f;
    float s = 0.f, s2 = 0.f;
    for (int jb = 0; jb < 16; ++jb) {
        float4 xa = x4[jb * 2];
        float4 xb = x4[jb * 2 + 1];
        float xv[8] = {xa.x, xa.y, xa.z, xa.w, xb.x, xb.y, xb.z, xb.w};
#pragma unroll
        for (int jj = 0; jj < 8; ++jj) {
            float xx = xv[jj];
            s += xx;
            s2 = fmaf(xx, xx, s2);
            const float* wrow = wWz + (jb * 8 + jj) * 16;
#pragma unroll
            for (int h = 0; h < 16; ++h)
                acc[h] = fmaf(xx, wrow[h], acc[h]);
        }
    }
    float mu  = s * (1.f / 128.f);
    float var = s2 * (1.f / 128.f) - mu * mu;
    float rs  = rsqrtf(var + EPSV);
#pragma unroll
    for (int h = 0; h < 16; ++h) {
        float v = rs * (acc[h] - mu * cc[h]) + cc[16 + h];
        zb[((size_t)h << 20) + row] = __float2bfloat16(v);
    }
}

// ---------------------------------------------------------------------------
// attn: grid (kc=8, qb=4, h=16), block 256 (4 waves). lane = q row.
__global__ __launch_bounds__(256) void attn_kernel(
    const float* __restrict__ qT, const float* __restrict__ kT,
    const float* __restrict__ vT, const __hip_bfloat16* __restrict__ zb,
    float* __restrict__ pm, float* __restrict__ pl, float* __restrict__ pO)
{
    const int kc = blockIdx.x, qb = blockIdx.y, h = blockIdx.z;
    const int lane = threadIdx.x & 63, wv = threadIdx.x >> 6;
    const int q = qb * 256 + wv * 64 + lane;

    const float* qp = qT + (((size_t)h << 10) + q) * 32;
    float qv[32];
#pragma unroll
    for (int u = 0; u < 8; ++u) {
        float4 t4 = *(const float4*)(qp + u * 4);
        qv[u * 4] = t4.x; qv[u * 4 + 1] = t4.y; qv[u * 4 + 2] = t4.z; qv[u * 4 + 3] = t4.w;
    }
    float O[32];
#pragma unroll
    for (int j = 0; j < 32; ++j) O[j] = 0.f;
    float m = -1e30f, l = 0.f;

    const __hip_bfloat16* zrow = zb + ((size_t)h << 20) + ((size_t)q << 10) + kc * 128;
    const float* kbase = kT + (((size_t)h << 10)) * 32;
    const float* vbase = vT + (((size_t)h << 10)) * 32;

    for (int kk0 = 0; kk0 < 128; kk0 += 16) {
        float sc[16];
#pragma unroll
        for (int t = 0; t < 16; ++t) {
            const float* kv = kbase + (size_t)(kc * 128 + kk0 + t) * 32;
            float d = 0.f;
#pragma unroll
            for (int j = 0; j < 32; ++j) d = fmaf(qv[j], kv[j], d);
            sc[t] = d + __bfloat162float(zrow[kk0 + t]);
        }
        float cm = m;
#pragma unroll
        for (int t = 0; t < 16; ++t) cm = fmaxf(cm, sc[t]);
        float scale = __expf(m - cm);
        m = cm;
        l *= scale;
#pragma unroll
        for (int j = 0; j < 32; ++j) O[j] *= scale;
#pragma unroll
        for (int t = 0; t < 16; ++t) {
            float p = __expf(sc[t] - m);
            l += p;
            const float* vv = vbase + (size_t)(kc * 128 + kk0 + t) * 32;
#pragma unroll
            for (int j = 0; j < 32; ++j) O[j] = fmaf(p, vv[j], O[j]);
        }
    }

    const size_t idx = ((size_t)kc * 16 + h) * 1024 + q;
    pm[idx] = m;
    pl[idx] = l;
    float* po = pO + idx * 32;
#pragma unroll
    for (int u = 0; u < 8; ++u) {
        *(float4*)(po + u * 4) =
            make_float4(O[u * 4], O[u * 4 + 1], O[u * 4 + 2], O[u * 4 + 3]);
    }
}

// ---------------------------------------------------------------------------
// combine: merge 8 k-chunk partials; apply sigmoid gate. t -> q*512+h*32+j.
__global__ __launch_bounds__(256) void combine_kernel(
    const float* __restrict__ pm, const float* __restrict__ pl,
    const float* __restrict__ pO, const float* __restrict__ gS,
    float* __restrict__ og)
{
    const int t = blockIdx.x * 256 + threadIdx.x;
    const int j = t & 31;
    const int hh = (t >> 5) & 15;
    const int q = t >> 9;
    const size_t base = ((size_t)hh << 10) + q;
    float ms[8];
    float M = -1e30f;
#pragma unroll
    for (int kc = 0; kc < 8; ++kc) {
        ms[kc] = pm[(size_t)kc * 16384 + base];
        M = fmaxf(M, ms[kc]);
    }
    float L = 0.f, O = 0.f;
#pragma unroll
    for (int kc = 0; kc < 8; ++kc) {
        float e = __expf(ms[kc] - M);
        L += pl[(size_t)kc * 16384 + base] * e;
        O += pO[((size_t)kc * 16384 + base) * 32 + j] * e;
    }
    og[t] = (O / L) * gS[t];
}

// ---------------------------------------------------------------------------
// out projection: og [1024,512] @ Wo [512,512] -> d_out
__global__ __launch_bounds__(256) void gemm_out_kernel(
    const float* __restrict__ A, const float* __restrict__ B,
    float* __restrict__ C)
{
    __shared__ float As[32][68];
    __shared__ float Bs[32][64];
    const int n0 = blockIdx.x * 64, m0 = blockIdx.y * 64;
    const int tid = threadIdx.x, tn = tid & 15, tm = tid >> 4;
    float acc[4][4] = {};

    for (int k0 = 0; k0 < 512; k0 += 32) {
#pragma unroll
        for (int u = 0; u < 2; ++u) {
            int f = tid * 2 + u;
            int i = f >> 3, kk4 = f & 7;
            float4 a4 = *(const float4*)(A + (size_t)(m0 + i) * 512 + k0 + kk4 * 4);
            As[kk4 * 4 + 0][i] = a4.x;
            As[kk4 * 4 + 1][i] = a4.y;
            As[kk4 * 4 + 2][i] = a4.z;
            As[kk4 * 4 + 3][i] = a4.w;
            int kk = f >> 4, j4 = f & 15;
            *(float4*)&Bs[kk][j4 * 4] =
                *(const float4*)(B + (size_t)(k0 + kk) * 512 + n0 + j4 * 4);
        }
        __syncthreads();
#pragma unroll
        for (int kk = 0; kk < 32; ++kk) {
            float a[4], b[4];
            *(float4*)a = *(const float4*)&As[kk][tm * 4];
            *(float4*)b = *(const float4*)&Bs[kk][tn * 4];
#pragma unroll
            for (int i = 0; i < 4; ++i)
#pragma unroll
                for (int j = 0; j < 4; ++j)
                    acc[i][j] = fmaf(a[i], b[j], acc[i][j]);
        }
        __syncthreads();
    }
#pragma unroll
    for (int i = 0; i < 4; ++i) {
        float* p = C + (size_t)(m0 + tm * 4 + i) * 512 + n0 + tn * 4;
        *(float4*)p = make_float4(acc[i][0], acc[i][1], acc[i][2], acc[i][3]);
    }
}

// ---------------------------------------------------------------------------
extern "C" void kernel_launch(void* const* d_in, const int* in_sizes, int n_in,
                              void* d_out, int out_size, void* d_ws, size_t ws_size,
                              hipStream_t stream)
{
    const float* s   = (const float*)d_in[0];
    const float* z   = (const float*)d_in[1];
    const float* nsw = (const float*)d_in[2];
    const float* nsb = (const float*)d_in[3];
    const float* Wq  = (const float*)d_in[4];
    const float* bq  = (const float*)d_in[5];
    const float* Wk  = (const float*)d_in[6];
    const float* Wv  = (const float*)d_in[7];
    const float* Wg  = (const float*)d_in[8];
    const float* znw = (const float*)d_in[9];
    const float* znb = (const float*)d_in[10];
    const float* Wz  = (const float*)d_in[11];
    const float* Wo  = (const float*)d_in[12];

    char* w = (char*)d_ws;
    float*          s_norm = (float*)(w + OFF_SNORM);
    float*          qT     = (float*)(w + OFF_QT);
    float*          kT     = (float*)(w + OFF_KT);
    float*          vT     = (float*)(w + OFF_VT);
    float*          gS     = (float*)(w + OFF_GS);
    __hip_bfloat16* zb     = (__hip_bfloat16*)(w + OFF_ZB);
    float*          wWz    = (float*)(w + OFF_WWZ);
    float*          cc     = (float*)(w + OFF_CC);
    float*          pm     = (float*)(w + OFF_PM);
    float*          pl     = (float*)(w + OFF_PL);
    float*          pO     = (float*)(w + OFF_PO);
    float*          og     = (float*)(w + OFF_OG);

    prep_w_kernel<<<dim3(1), dim3(256), 0, stream>>>(znw, znb, Wz, wWz, cc);
    lns_kernel<<<dim3(256), dim3(256), 0, stream>>>(s, nsw, nsb, s_norm);
    gemm_qkvg_kernel<<<dim3(4, 8, 4), dim3(256), 0, stream>>>(
        s_norm, Wq, Wk, Wv, Wg, bq, qT, kT, vT, gS);
    zbias_kernel<<<dim3(4096), dim3(256), 0, stream>>>(z, wWz, cc, zb);
    attn_kernel<<<dim3(8, 4, 16), dim3(256), 0, stream>>>(qT, kT, vT, zb, pm, pl, pO);
    combine_kernel<<<dim3(2048), dim3(256), 0, stream>>>(pm, pl, pO, gS, og);
    gemm_out_kernel<<<dim3(8, 16), dim3(256), 0, stream>>>(og, Wo, (float*)d_out);
}

// Round 2
// 796.151 us; speedup vs baseline: 1.2417x; 1.2417x over previous
//
#include <hip/hip_runtime.h>

// ---------------------------------------------------------------------------
// AttentionPairBias: B=1, N=1024, H=16, HD=32, D=512, DZ=128
// bf16 MFMA pipeline:
//   prep_w : wzt[h][j] = bf16(z_norm_w[j]*Wz[j][h]); cc = {csum[16], cb[16]}
//   convw  : WT[mat][n][k] = bf16(W[k][n]) for Wq,Wk,Wv,Wg,Wo (transposed)
//   lns    : sbf = bf16(LN(s))                       [1024,512]
//   zbias  : per 64-row tile: stage z f32->bf16 LDS, f32 stats,
//            MFMA (A=wzt [16h x 128k], B=X^T) -> zb[h][q*1024+k] bf16
//   gemm_qkvg: direct-fragment MFMA, epilogues -> qT,kT (bf16 [h][n][32],
//            q has +bq, *HD^-0.5), vTt (bf16 [h][32][1024]), gS (f32 [n][512])
//   attn   : flash, 1 wave = 16 q rows, full 1024 k sweep, MFMA QK^T + PV,
//            P relayout via wave-private LDS, gate fused -> og bf16 [n][512]
//   gemm_out: og @ WoT -> d_out f32
// MFMA 16x16x32 layouts (m89/m74-verified family):
//   A: row=l&15, k=(l>>4)*8+i ; B: col=l&15, k=(l>>4)*8+i
//   C/D: col=l&15, row=(l>>4)*4+r
// ---------------------------------------------------------------------------

#define EPSV 1e-5f

typedef __bf16 bf16x8 __attribute__((ext_vector_type(8)));
typedef float f32x4 __attribute__((ext_vector_type(4)));
typedef unsigned short ushort8 __attribute__((ext_vector_type(8)));
typedef unsigned short ushort4v __attribute__((ext_vector_type(4)));

__device__ __forceinline__ unsigned short f2b(float f) {
    unsigned int u = __float_as_uint(f);
    u += 0x7fffu + ((u >> 16) & 1u);
    return (unsigned short)(u >> 16);
}
__device__ __forceinline__ float b2f(unsigned short h) {
    return __uint_as_float(((unsigned int)h) << 16);
}
__device__ __forceinline__ f32x4 mfma16(bf16x8 a, bf16x8 b, f32x4 c) {
    return __builtin_amdgcn_mfma_f32_16x16x32_bf16(a, b, c, 0, 0, 0);
}

// ---------------- ws layout (bytes) ----------------
#define OFF_SBF 0u            // bf16 [1024][512]   = 1 MB
#define OFF_WT  1048576u      // bf16 5x[512][512]  = 2.5 MB (q,k,v,g,o)
#define OFF_QT  3670016u      // bf16 [16][1024][32]
#define OFF_KT  4718592u
#define OFF_VT  5767168u      // bf16 [16][32][1024]
#define OFF_GS  6815744u      // f32  [1024][512]   = 2 MB
#define OFF_OG  8912896u      // bf16 [1024][512]   = 1 MB
#define OFF_WZT 9961472u      // bf16 [16][128]
#define OFF_CC  9965568u      // f32  [32]
#define OFF_ZB  9965696u      // bf16 [16][1024*1024] = 32 MB

// ---------------------------------------------------------------------------
__global__ __launch_bounds__(256) void prep_w_kernel(
    const float* __restrict__ znw, const float* __restrict__ znb,
    const float* __restrict__ Wz, unsigned short* __restrict__ wzt,
    float* __restrict__ cc)
{
    const int t = threadIdx.x;
#pragma unroll
    for (int u = 0; u < 8; ++u) {
        int idx = t + u * 256;          // idx = j*16 + h
        int j = idx >> 4, h = idx & 15;
        wzt[h * 128 + j] = f2b(znw[j] * Wz[idx]);
    }
    if (t < 16) {
        float cs = 0.f, cb = 0.f;
        for (int j = 0; j < 128; ++j) {
            float wv = Wz[j * 16 + t];
            cs += znw[j] * wv;
            cb += znb[j] * wv;
        }
        cc[t] = cs;
        cc[16 + t] = cb;
    }
}

// ---------------------------------------------------------------------------
// transpose-convert 5 weight matrices f32 [512k][512n] -> bf16 [n][k]
__global__ __launch_bounds__(256) void convw_kernel(
    const float* __restrict__ Wq, const float* __restrict__ Wk,
    const float* __restrict__ Wv, const float* __restrict__ Wg,
    const float* __restrict__ Wo, unsigned short* __restrict__ WT)
{
    int t = blockIdx.x * 256 + threadIdx.x;     // 640 blocks: 5*512*64 threads
    int mat = t >> 15;
    int r = t & 32767;
    int n = r & 511;
    int k0 = (r >> 9) * 8;
    const float* W = mat == 0 ? Wq : mat == 1 ? Wk : mat == 2 ? Wv : mat == 3 ? Wg : Wo;
    ushort8 o;
#pragma unroll
    for (int i = 0; i < 8; ++i)
        o[i] = f2b(W[(size_t)(k0 + i) * 512 + n]);
    *(ushort8*)(WT + (size_t)mat * 262144 + (size_t)n * 512 + k0) = o;
}

// ---------------------------------------------------------------------------
__global__ __launch_bounds__(256) void lns_kernel(
    const float* __restrict__ s, const float* __restrict__ w,
    const float* __restrict__ b, unsigned short* __restrict__ sbf)
{
    const int lane = threadIdx.x & 63;
    const int wv   = threadIdx.x >> 6;
    const int row  = blockIdx.x * 4 + wv;
    const float* x = s + (size_t)row * 512 + lane * 8;
    float4 a = *(const float4*)x;
    float4 c = *(const float4*)(x + 4);
    float v[8] = {a.x, a.y, a.z, a.w, c.x, c.y, c.z, c.w};
    float ss = 0.f, s2 = 0.f;
#pragma unroll
    for (int u = 0; u < 8; ++u) { ss += v[u]; s2 = fmaf(v[u], v[u], s2); }
#pragma unroll
    for (int m = 1; m < 64; m <<= 1) {
        ss += __shfl_xor(ss, m);
        s2 += __shfl_xor(s2, m);
    }
    float mu  = ss * (1.f / 512.f);
    float var = s2 * (1.f / 512.f) - mu * mu;
    float rs  = rsqrtf(var + EPSV);
    ushort8 ob;
#pragma unroll
    for (int u = 0; u < 8; ++u)
        ob[u] = f2b((v[u] - mu) * rs * w[lane * 8 + u] + b[lane * 8 + u]);
    *(ushort8*)(sbf + (size_t)row * 512 + lane * 8) = ob;
}

// ---------------------------------------------------------------------------
// zbias: 64 z-rows per block. Stage z->bf16 LDS (padded stride 136), f32
// stats, then MFMA: C[h][zrow] = wzt[16hx128k] @ X^T; LN correction applied
// in epilogue: zb = rs*(C - mu*cs) + cb. Writes zb[h][row] (32B segments).
__global__ __launch_bounds__(256) void zbias_kernel(
    const float* __restrict__ z, const unsigned short* __restrict__ wzt,
    const float* __restrict__ cc, unsigned short* __restrict__ zb)
{
    __shared__ unsigned short xb[64 * 136];   // 17408 B
    __shared__ float mus[64], rss[64], ccs[32];
    const int t = threadIdx.x;
    const size_t rowbase = (size_t)blockIdx.x * 64;

    if (t < 32) ccs[t] = cc[t];
    const float4* zsrc = (const float4*)(z + rowbase * 128);
#pragma unroll
    for (int u = 0; u < 8; ++u) {
        int g = t + u * 256;                  // 2048 float4 = 64 rows x 32
        float4 v = zsrc[g];
        int row = g >> 5, c4 = g & 31;
        ushort4v pk;
        pk[0] = f2b(v.x); pk[1] = f2b(v.y); pk[2] = f2b(v.z); pk[3] = f2b(v.w);
        *(ushort4v*)(xb + row * 136 + c4 * 4) = pk;
    }
    __syncthreads();

    {   // stats: 4 threads per row, 32 elems each, shfl-combine
        int row = t >> 2, seg = t & 3;
        const unsigned short* xr = xb + row * 136 + seg * 32;
        float s1 = 0.f, s2 = 0.f;
#pragma unroll
        for (int i = 0; i < 8; ++i) {
            ushort4v v = *(const ushort4v*)(xr + i * 4);
#pragma unroll
            for (int j = 0; j < 4; ++j) {
                float x = b2f(v[j]);
                s1 += x;
                s2 = fmaf(x, x, s2);
            }
        }
        s1 += __shfl_xor(s1, 1); s2 += __shfl_xor(s2, 1);
        s1 += __shfl_xor(s1, 2); s2 += __shfl_xor(s2, 2);
        if (seg == 0) {
            float mu = s1 * (1.f / 128.f);
            float var = s2 * (1.f / 128.f) - mu * mu;
            mus[row] = mu;
            rss[row] = rsqrtf(var + EPSV);
        }
    }
    __syncthreads();

    const int w = t >> 6, l = t & 63, lr = l & 15, lg = l >> 4;
    // A-frags: wzt rows (h = lr), k = c*32 + lg*8
    bf16x8 awz[4];
#pragma unroll
    for (int c = 0; c < 4; ++c)
        awz[c] = *(const bf16x8*)(wzt + lr * 128 + c * 32 + lg * 8);
    const unsigned short* xw = xb + (w * 16) * 136;
    f32x4 acc = {0.f, 0.f, 0.f, 0.f};
#pragma unroll
    for (int c = 0; c < 4; ++c) {
        bf16x8 bx = *(const bf16x8*)(xw + lr * 136 + c * 32 + lg * 8);
        acc = mfma16(awz[c], bx, acc);
    }
    // C: row = h = lg*4+r, col = local z-row = lr
    const int zl = w * 16 + lr;
    const float mu = mus[zl], rs = rss[zl];
    const size_t zr = rowbase + zl;
#pragma unroll
    for (int r = 0; r < 4; ++r) {
        int hh = lg * 4 + r;
        float val = rs * (acc[r] - mu * ccs[hh]) + ccs[16 + hh];
        zb[((size_t)hh << 20) + zr] = f2b(val);
    }
}

// ---------------------------------------------------------------------------
// QKVG: direct-fragment MFMA GEMM. grid (8 n-tiles of 64, 4 m-groups, 4 which).
// wave w handles m-tile blockIdx.y*4+w (64 rows) x n-tile (64 cols).
__global__ __launch_bounds__(256) void gemm_qkvg_kernel(
    const unsigned short* __restrict__ sbf, const unsigned short* __restrict__ WT,
    const float* __restrict__ bq,
    unsigned short* __restrict__ qT, unsigned short* __restrict__ kT,
    unsigned short* __restrict__ vTt, float* __restrict__ gS)
{
    const int which = blockIdx.z;
    const unsigned short* BT = WT + (size_t)which * 262144;   // [n][k]
    const int w = threadIdx.x >> 6, l = threadIdx.x & 63;
    const int lr = l & 15, lg = l >> 4;
    const int m0 = (blockIdx.y * 4 + w) * 64;
    const int n0 = blockIdx.x * 64;

    f32x4 acc[4][4];
#pragma unroll
    for (int i = 0; i < 4; ++i)
#pragma unroll
        for (int j = 0; j < 4; ++j) acc[i][j] = (f32x4){0.f, 0.f, 0.f, 0.f};

    for (int k0 = 0; k0 < 512; k0 += 32) {
        bf16x8 a[4], b[4];
#pragma unroll
        for (int fm = 0; fm < 4; ++fm)
            a[fm] = *(const bf16x8*)(sbf + (size_t)(m0 + fm * 16 + lr) * 512 + k0 + lg * 8);
#pragma unroll
        for (int fn = 0; fn < 4; ++fn)
            b[fn] = *(const bf16x8*)(BT + (size_t)(n0 + fn * 16 + lr) * 512 + k0 + lg * 8);
#pragma unroll
        for (int fm = 0; fm < 4; ++fm)
#pragma unroll
            for (int fn = 0; fn < 4; ++fn)
                acc[fm][fn] = mfma16(a[fm], b[fn], acc[fm][fn]);
    }

    if (which == 3) {
#pragma unroll
        for (int fm = 0; fm < 4; ++fm)
#pragma unroll
            for (int fn = 0; fn < 4; ++fn) {
                int c = n0 + fn * 16 + lr;
#pragma unroll
                for (int r = 0; r < 4; ++r) {
                    int m = m0 + fm * 16 + lg * 4 + r;
                    gS[(size_t)m * 512 + c] = 1.f / (1.f + __expf(-acc[fm][fn][r]));
                }
            }
    } else if (which == 2) {
#pragma unroll
        for (int fm = 0; fm < 4; ++fm)
#pragma unroll
            for (int fn = 0; fn < 4; ++fn) {
                int c = n0 + fn * 16 + lr;
                int hh = c >> 5, d = c & 31;
#pragma unroll
                for (int r = 0; r < 4; ++r) {
                    int m = m0 + fm * 16 + lg * 4 + r;
                    vTt[(size_t)hh * 32768 + (size_t)d * 1024 + m] = f2b(acc[fm][fn][r]);
                }
            }
    } else {
        unsigned short* dst = (which == 0) ? qT : kT;
        const float scl = (which == 0) ? 0.17677669529663687f : 1.f;
#pragma unroll
        for (int fm = 0; fm < 4; ++fm)
#pragma unroll
            for (int fn = 0; fn < 4; ++fn) {
                int c = n0 + fn * 16 + lr;
                int hh = c >> 5, d = c & 31;
                float bb = (which == 0) ? bq[c] : 0.f;
#pragma unroll
                for (int r = 0; r < 4; ++r) {
                    int m = m0 + fm * 16 + lg * 4 + r;
                    dst[(size_t)hh * 32768 + (size_t)m * 32 + d] = f2b((acc[fm][fn][r] + bb) * scl);
                }
            }
    }
}

// ---------------------------------------------------------------------------
// attn: grid (16 qb, 16 h), block 256 = 4 waves; wave handles 16 q-rows,
// sweeps all 1024 keys in 32-chunks. P relayout via wave-private LDS tile.
__global__ __launch_bounds__(256) void attn_kernel(
    const unsigned short* __restrict__ qT, const unsigned short* __restrict__ kT,
    const unsigned short* __restrict__ vTt, const unsigned short* __restrict__ zb,
    const float* __restrict__ gS, unsigned short* __restrict__ og)
{
    __shared__ unsigned short plds[4][16 * 48];     // padded stride 48
    const int w = threadIdx.x >> 6, l = threadIdx.x & 63;
    const int lr = l & 15, lg = l >> 4;
    const int h = blockIdx.y;
    const int q0 = blockIdx.x * 64 + w * 16;

    const unsigned short* qh = qT + (size_t)h * 32768;
    const unsigned short* kh = kT + (size_t)h * 32768;
    const unsigned short* vh = vTt + (size_t)h * 32768;
    const unsigned short* zrow = zb + ((size_t)h << 20);
    unsigned short* pw = plds[w];

    const bf16x8 qa = *(const bf16x8*)(qh + (size_t)(q0 + lr) * 32 + lg * 8);
    f32x4 o0 = {0.f, 0.f, 0.f, 0.f}, o1 = {0.f, 0.f, 0.f, 0.f};
    float m[4] = {-1e30f, -1e30f, -1e30f, -1e30f};
    float lsum[4] = {0.f, 0.f, 0.f, 0.f};

    for (int kb = 0; kb < 1024; kb += 32) {
        bf16x8 kf0 = *(const bf16x8*)(kh + (size_t)(kb + lr) * 32 + lg * 8);
        bf16x8 kf1 = *(const bf16x8*)(kh + (size_t)(kb + 16 + lr) * 32 + lg * 8);
        bf16x8 vf0 = *(const bf16x8*)(vh + (size_t)lr * 1024 + kb + lg * 8);
        bf16x8 vf1 = *(const bf16x8*)(vh + (size_t)(16 + lr) * 1024 + kb + lg * 8);
        f32x4 zero = {0.f, 0.f, 0.f, 0.f};
        f32x4 s0 = mfma16(qa, kf0, zero);
        f32x4 s1 = mfma16(qa, kf1, zero);
#pragma unroll
        for (int r = 0; r < 4; ++r) {
            int qr = q0 + lg * 4 + r;
            s0[r] += b2f(zrow[(size_t)qr * 1024 + kb + lr]);
            s1[r] += b2f(zrow[(size_t)qr * 1024 + kb + 16 + lr]);
        }
#pragma unroll
        for (int r = 0; r < 4; ++r) {
            float mx = fmaxf(s0[r], s1[r]);
            mx = fmaxf(mx, __shfl_xor(mx, 1));
            mx = fmaxf(mx, __shfl_xor(mx, 2));
            mx = fmaxf(mx, __shfl_xor(mx, 4));
            mx = fmaxf(mx, __shfl_xor(mx, 8));
            float mn = fmaxf(m[r], mx);
            float f = __expf(m[r] - mn);
            m[r] = mn;
            float p0 = __expf(s0[r] - mn);
            float p1 = __expf(s1[r] - mn);
            float rsum = p0 + p1;
            rsum += __shfl_xor(rsum, 1);
            rsum += __shfl_xor(rsum, 2);
            rsum += __shfl_xor(rsum, 4);
            rsum += __shfl_xor(rsum, 8);
            lsum[r] = lsum[r] * f + rsum;
            o0[r] *= f;
            o1[r] *= f;
            pw[(lg * 4 + r) * 48 + lr]      = f2b(p0);
            pw[(lg * 4 + r) * 48 + 16 + lr] = f2b(p1);
        }
        bf16x8 pa = *(const bf16x8*)(pw + lr * 48 + lg * 8);
        o0 = mfma16(pa, vf0, o0);
        o1 = mfma16(pa, vf1, o1);
    }
#pragma unroll
    for (int r = 0; r < 4; ++r) {
        int qr = q0 + lg * 4 + r;
        float inv = 1.f / lsum[r];
        int c = (h << 5) + lr;
        og[(size_t)qr * 512 + c]      = f2b(o0[r] * inv * gS[(size_t)qr * 512 + c]);
        og[(size_t)qr * 512 + c + 16] = f2b(o1[r] * inv * gS[(size_t)qr * 512 + c + 16]);
    }
}

// ---------------------------------------------------------------------------
// out projection: og bf16 [1024][512] @ WoT [512n][512k] -> out f32.
// grid (16 n-tiles of 32, 4 m-groups), wave tile 64x32.
__global__ __launch_bounds__(256) void gemm_out_kernel(
    const unsigned short* __restrict__ og, const unsigned short* __restrict__ WoT,
    float* __restrict__ out)
{
    const int w = threadIdx.x >> 6, l = threadIdx.x & 63;
    const int lr = l & 15, lg = l >> 4;
    const int m0 = (blockIdx.y * 4 + w) * 64;
    const int n0 = blockIdx.x * 32;

    f32x4 acc[4][2];
#pragma unroll
    for (int i = 0; i < 4; ++i)
#pragma unroll
        for (int j = 0; j < 2; ++j) acc[i][j] = (f32x4){0.f, 0.f, 0.f, 0.f};

    for (int k0 = 0; k0 < 512; k0 += 32) {
        bf16x8 a[4], b[2];
#pragma unroll
        for (int fm = 0; fm < 4; ++fm)
            a[fm] = *(const bf16x8*)(og + (size_t)(m0 + fm * 16 + lr) * 512 + k0 + lg * 8);
#pragma unroll
        for (int fn = 0; fn < 2; ++fn)
            b[fn] = *(const bf16x8*)(WoT + (size_t)(n0 + fn * 16 + lr) * 512 + k0 + lg * 8);
#pragma unroll
        for (int fm = 0; fm < 4; ++fm)
#pragma unroll
            for (int fn = 0; fn < 2; ++fn)
                acc[fm][fn] = mfma16(a[fm], b[fn], acc[fm][fn]);
    }
#pragma unroll
    for (int fm = 0; fm < 4; ++fm)
#pragma unroll
        for (int fn = 0; fn < 2; ++fn) {
            int c = n0 + fn * 16 + lr;
#pragma unroll
            for (int r = 0; r < 4; ++r) {
                int m = m0 + fm * 16 + lg * 4 + r;
                out[(size_t)m * 512 + c] = acc[fm][fn][r];
            }
        }
}

// ---------------------------------------------------------------------------
extern "C" void kernel_launch(void* const* d_in, const int* in_sizes, int n_in,
                              void* d_out, int out_size, void* d_ws, size_t ws_size,
                              hipStream_t stream)
{
    const float* s   = (const float*)d_in[0];
    const float* z   = (const float*)d_in[1];
    const float* nsw = (const float*)d_in[2];
    const float* nsb = (const float*)d_in[3];
    const float* Wq  = (const float*)d_in[4];
    const float* bq  = (const float*)d_in[5];
    const float* Wk  = (const float*)d_in[6];
    const float* Wv  = (const float*)d_in[7];
    const float* Wg  = (const float*)d_in[8];
    const float* znw = (const float*)d_in[9];
    const float* znb = (const float*)d_in[10];
    const float* Wz  = (const float*)d_in[11];
    const float* Wo  = (const float*)d_in[12];

    char* wsb = (char*)d_ws;
    unsigned short* sbf = (unsigned short*)(wsb + OFF_SBF);
    unsigned short* WT  = (unsigned short*)(wsb + OFF_WT);
    unsigned short* qT  = (unsigned short*)(wsb + OFF_QT);
    unsigned short* kT  = (unsigned short*)(wsb + OFF_KT);
    unsigned short* vTt = (unsigned short*)(wsb + OFF_VT);
    float*          gS  = (float*)(wsb + OFF_GS);
    unsigned short* og  = (unsigned short*)(wsb + OFF_OG);
    unsigned short* wzt = (unsigned short*)(wsb + OFF_WZT);
    float*          cc  = (float*)(wsb + OFF_CC);
    unsigned short* zbp = (unsigned short*)(wsb + OFF_ZB);

    prep_w_kernel<<<dim3(1), dim3(256), 0, stream>>>(znw, znb, Wz, wzt, cc);
    convw_kernel<<<dim3(640), dim3(256), 0, stream>>>(Wq, Wk, Wv, Wg, Wo, WT);
    lns_kernel<<<dim3(256), dim3(256), 0, stream>>>(s, nsw, nsb, sbf);
    zbias_kernel<<<dim3(16384), dim3(256), 0, stream>>>(z, wzt, cc, zbp);
    gemm_qkvg_kernel<<<dim3(8, 4, 4), dim3(256), 0, stream>>>(
        sbf, WT, bq, qT, kT, vTt, gS);
    attn_kernel<<<dim3(16, 16), dim3(256), 0, stream>>>(qT, kT, vTt, zbp, gS, og);
    gemm_out_kernel<<<dim3(16, 4), dim3(256), 0, stream>>>(og, WT + 4 * 262144, (float*)d_out);
}